// Round 7
// baseline (140.960 us; speedup 1.0000x reference)
//
#include <hip/hip_runtime.h>

typedef __bf16 bf16;
typedef __bf16 bf16x4 __attribute__((ext_vector_type(4)));
typedef __bf16 bf16x8 __attribute__((ext_vector_type(8)));
typedef float  f32x4  __attribute__((ext_vector_type(4)));

#define T_DIM 256
#define B_DIM 256
#define NIN   512
#define NH    512
#define NEMB  256
#define NX    768      // NIN + NEMB
#define NG    1536     // 3*NH

__device__ __forceinline__ float fast_tanh(float x) {
    float e = __expf(2.0f * x);
    return 1.0f - 2.0f * __builtin_amdgcn_rcpf(e + 1.0f);
}
__device__ __forceinline__ float fast_sigmoid(float x) {
    return __builtin_amdgcn_rcpf(1.0f + __expf(-x));
}

__device__ __forceinline__ void gload_lds16(const bf16* g, bf16* l) {
    __builtin_amdgcn_global_load_lds(
        (const __attribute__((address_space(1))) void*)g,
        (__attribute__((address_space(3))) void*)l, 16, 0, 0);
}

// element-index XOR swizzle for 32-elem rows (measured 0 conflicts in v3/v4)
__device__ __forceinline__ int swz(int rc) { return ((rc >> 1) & 3) << 3; }

// ---------------- weight/h conversion; w_i2h -> swizzled K-step image ----------------
// Wimg[kk][col][k ^ swz(col)] = w_i2h[col][kk*32+k]   (kk<16, col<512, k<32)
__global__ __launch_bounds__(256) void cvt_weights(
    const float* __restrict__ a0, const float* __restrict__ a1,
    const float* __restrict__ a2, const float* __restrict__ a3,
    const float* __restrict__ a4,
    bf16* __restrict__ b0, bf16* __restrict__ b1, bf16* __restrict__ b2,
    bf16* __restrict__ b3, bf16* __restrict__ b4) {
    const int N0 = 65536, N1 = 131072, N2 = 425984, N3 = 622592, N4 = 655360;
    for (int i = blockIdx.x * 256 + threadIdx.x; i < N4; i += gridDim.x * 256) {
        const float* s; bf16* d; int j; bool img = false;
        if (i < N0)      { s = a0; d = b0; j = i; img = true; }
        else if (i < N1) { s = a1; d = b1; j = i - N0; }
        else if (i < N2) { s = a2; d = b2; j = i - N1; }
        else if (i < N3) { s = a3; d = b3; j = i - N2; }
        else             { s = a4; d = b4; j = i - N3; }
        float4 v = reinterpret_cast<const float4*>(s)[j];
        bf16x4 o = { (bf16)v.x, (bf16)v.y, (bf16)v.z, (bf16)v.w };
        if (img) {
            int e = j * 4, col = e >> 9, kc = e & 511, kk = kc >> 5, k = kc & 31;
            int off = kk * 16384 + col * 32 + (k ^ swz(col));
            *reinterpret_cast<bf16x4*>(d + off) = o;
        } else {
            reinterpret_cast<bf16x4*>(d)[j] = o;
        }
    }
}

// ---------------- generic GEMM: C[M,N] = A[M,K] * B[N,K]^T + bias[N] ----------------
__global__ __launch_bounds__(256) void gemm_bias(
    const bf16* __restrict__ A, const bf16* __restrict__ B,
    const float* __restrict__ bias, float* __restrict__ C,
    int M, int N, int K) {
    __shared__ bf16 At[64][40];
    __shared__ bf16 Bt[64][40];
    const int tid = threadIdx.x;
    const int m0 = blockIdx.y * 64, n0 = blockIdx.x * 64;
    const int wid = tid >> 6, lane = tid & 63, hi = lane >> 4, lo = lane & 15;
    const int srow = tid >> 2, sseg = tid & 3;
    f32x4 acc[4] = {};

    for (int kk = 0; kk < K; kk += 32) {
        bf16x8 av = *reinterpret_cast<const bf16x8*>(A + (size_t)(m0 + srow) * K + kk + sseg * 8);
        bf16x8 bv = *reinterpret_cast<const bf16x8*>(B + (size_t)(n0 + srow) * K + kk + sseg * 8);
        __syncthreads();
        *reinterpret_cast<bf16x8*>(&At[srow][sseg * 8]) = av;
        *reinterpret_cast<bf16x8*>(&Bt[srow][sseg * 8]) = bv;
        __syncthreads();
        bf16x8 a = *reinterpret_cast<const bf16x8*>(&At[wid * 16 + lo][hi * 8]);
#pragma unroll
        for (int nt = 0; nt < 4; ++nt) {
            bf16x8 b = *reinterpret_cast<const bf16x8*>(&Bt[nt * 16 + lo][hi * 8]);
            acc[nt] = __builtin_amdgcn_mfma_f32_16x16x32_bf16(a, b, acc[nt], 0, 0, 0);
        }
    }
#pragma unroll
    for (int nt = 0; nt < 4; ++nt) {
        int n = n0 + nt * 16 + lo;
        float bv = bias[n];
#pragma unroll
        for (int r = 0; r < 4; ++r) {
            int m = m0 + wid * 16 + hi * 4 + r;
            C[(size_t)m * N + n] = acc[nt][r] + bv;
        }
    }
}

// ---------------- fused emit kernel (v6: m201-style counted-vmcnt pipeline) ----------------
// emit[m] = sum_n tanh((feats W^T)[m,n] + h_[b(m),n]) * w_score[n]
// 64 m-rows/block, 8 waves x 64 n-cols, K-step 32.
// B: 3-slot LDS ring, DMA'd 2 steps ahead (counted vmcnt, never drained in loop).
// A: f32->bf16 reg-staged into 2-buffer LDS, loads issued 2 steps ahead.
__global__ __launch_bounds__(512) void emit_kernel(
    const float* __restrict__ feats, const bf16* __restrict__ Wimg,
    const float* __restrict__ hbuf, const float* __restrict__ wscore,
    float* __restrict__ emit_out) {
    __shared__ bf16 Btile[3][16384];   // 96 KB: [slot][col*32 + (k^swz(col))]
    __shared__ bf16 Atile[2][2048];    // 8 KB:  [buf][row*32 + (k^swz(row))]
    const int tid = threadIdx.x;
    const int m0 = blockIdx.x * 64;
    const int wid = tid >> 6, lane = tid & 63, hi = lane >> 4, lo = lane & 15;

    // A staging coords
    const int arow = tid >> 3, akq = tid & 7;
    const int aoff = arow * 32 + ((akq * 4) ^ swz(arow));
    const float* asrc = feats + (size_t)(m0 + arow) * NIN + akq * 4;

    // ---- prologue: fa0, fa1, B0, B1 in flight; stage A0 ----
    float4 fav0 = *reinterpret_cast<const float4*>(asrc);          // fa(0)
    float4 fav1 = *reinterpret_cast<const float4*>(asrc + 32);     // fa(1)
#pragma unroll
    for (int r = 0; r < 4; ++r)
        gload_lds16(Wimg + 0 * 16384 + r * 4096 + wid * 512 + lane * 8,
                    &Btile[0][r * 4096 + wid * 512]);
#pragma unroll
    for (int r = 0; r < 4; ++r)
        gload_lds16(Wimg + 1 * 16384 + r * 4096 + wid * 512 + lane * 8,
                    &Btile[1][r * 4096 + wid * 512]);
    {   // cvt fa0 -> A buf 0  (compiler waits vmcnt(9): keeps fa1,B0,B1 in flight)
        bf16x4 o = { (bf16)fav0.x, (bf16)fav0.y, (bf16)fav0.z, (bf16)fav0.w };
        *reinterpret_cast<bf16x4*>(&Atile[0][aoff]) = o;
    }
    asm volatile("s_waitcnt lgkmcnt(0)" ::: "memory");
    __builtin_amdgcn_sched_barrier(0);

    f32x4 acc[4][4] = {};   // [nt][st]

#pragma unroll
    for (int kk = 0; kk < 16; ++kk) {
        // wait for B(kk) to land (counted: keeps fa(kk+1), B(kk+1) in flight)
        if (kk < 15) {
            asm volatile("s_waitcnt vmcnt(5)" ::: "memory");
        } else {
            asm volatile("s_waitcnt vmcnt(0)" ::: "memory");
        }
        __builtin_amdgcn_s_barrier();   // raw barrier: no vmcnt drain
        __builtin_amdgcn_sched_barrier(0);

        // issue 2-ahead loads AFTER the barrier (slot (kk+2)%3's readers are done)
        if (kk < 14) {
            if ((kk & 1) == 0)
                fav0 = *reinterpret_cast<const float4*>(asrc + (kk + 2) * 32);
            else
                fav1 = *reinterpret_cast<const float4*>(asrc + (kk + 2) * 32);
#pragma unroll
            for (int r = 0; r < 4; ++r)
                gload_lds16(Wimg + (kk + 2) * 16384 + r * 4096 + wid * 512 + lane * 8,
                            &Btile[(kk + 2) % 3][r * 4096 + wid * 512]);
        }

        // fragments for this step
        bf16x8 a[4], b[4];
#pragma unroll
        for (int st = 0; st < 4; ++st) {
            int row = st * 16 + lo;
            a[st] = *reinterpret_cast<const bf16x8*>(
                &Atile[kk & 1][row * 32 + ((hi * 8) ^ swz(row))]);
        }
#pragma unroll
        for (int nt = 0; nt < 4; ++nt) {
            int col = wid * 64 + nt * 16 + lo;
            b[nt] = *reinterpret_cast<const bf16x8*>(
                &Btile[kk % 3][col * 32 + ((hi * 8) ^ swz(col))]);
        }
#pragma unroll
        for (int nt = 0; nt < 4; ++nt)
#pragma unroll
            for (int st = 0; st < 4; ++st)
                acc[nt][st] = __builtin_amdgcn_mfma_f32_16x16x32_bf16(
                    a[st], b[nt], acc[nt][st], 0, 0, 0);

        // stage A(kk+1) (fa consumed here; compiler's vmcnt keeps B loads in flight)
        if (kk < 15) {
            float4 f = ((kk + 1) & 1) ? fav1 : fav0;
            bf16x4 o = { (bf16)f.x, (bf16)f.y, (bf16)f.z, (bf16)f.w };
            *reinterpret_cast<bf16x4*>(&Atile[(kk + 1) & 1][aoff]) = o;
            asm volatile("s_waitcnt lgkmcnt(0)" ::: "memory");
            __builtin_amdgcn_sched_barrier(0);
        }
    }

    // ---- epilogue: add h_, tanh, dot with w_score ----
    float ep[4][4] = {};                 // [st][r]
    const int bbase = m0 & (B_DIM - 1);
    const int n0 = wid * 64;
#pragma unroll
    for (int nt = 0; nt < 4; ++nt) {
        int n = n0 + nt * 16 + lo;
        float wsn = wscore[n];
#pragma unroll
        for (int st = 0; st < 4; ++st) {
#pragma unroll
            for (int r = 0; r < 4; ++r) {
                int b = bbase + st * 16 + hi * 4 + r;
                float x = acc[nt][st][r] + hbuf[(size_t)b * NH + n];
                ep[st][r] += fast_tanh(x) * wsn;
            }
        }
    }
#pragma unroll
    for (int st = 0; st < 4; ++st)
#pragma unroll
        for (int r = 0; r < 4; ++r)
#pragma unroll
            for (int off = 1; off < 16; off <<= 1)
                ep[st][r] += __shfl_xor(ep[st][r], off, 64);

    __syncthreads();                     // all K-loop LDS traffic complete
    float* ew = reinterpret_cast<float*>(&Atile[0][0]);   // 2 KB alias
    if (lo == 0) {
#pragma unroll
        for (int st = 0; st < 4; ++st)
#pragma unroll
            for (int r = 0; r < 4; ++r)
                ew[wid * 64 + st * 16 + hi * 4 + r] = ep[st][r];
    }
    __syncthreads();
    if (tid < 64) {
        float s = 0.0f;
#pragma unroll
        for (int ww = 0; ww < 8; ++ww) s += ew[ww * 64 + tid];
        emit_out[m0 + tid] = s;
    }
}

// ---------------- softmax over T (per column b) ----------------
__global__ __launch_bounds__(256) void softmax_t(
    const float* __restrict__ emit, float* __restrict__ alpha, float* __restrict__ out_alpha) {
    int b = blockIdx.x, t = threadIdx.x;
    int wv = t >> 6, ln = t & 63;
    float e = emit[(size_t)t * B_DIM + b];
    float m = e;
#pragma unroll
    for (int off = 32; off; off >>= 1) m = fmaxf(m, __shfl_xor(m, off, 64));
    __shared__ float red[4], red2[4];
    if (ln == 0) red[wv] = m;
    __syncthreads();
    m = fmaxf(fmaxf(red[0], red[1]), fmaxf(red[2], red[3]));
    float p = __expf(e - m);
    float s = p;
#pragma unroll
    for (int off = 32; off; off >>= 1) s += __shfl_xor(s, off, 64);
    if (ln == 0) red2[wv] = s;
    __syncthreads();
    float inv = __builtin_amdgcn_rcpf(red2[0] + red2[1] + red2[2] + red2[3]);
    float a = p * inv;
    alpha[(size_t)t * B_DIM + b] = a;
    out_alpha[(size_t)t * B_DIM + b] = a;
}

// ---------------- context + build_x fused (reads f32 feats, L3-resident) ----------------
__global__ __launch_bounds__(256) void ctx_kernel(
    const float* __restrict__ feats, const float* __restrict__ alpha,
    const float* __restrict__ emb, bf16* __restrict__ x) {
    int b = blockIdx.x;
    __shared__ float al[T_DIM];
    __shared__ float red[4][512];
    int tid = threadIdx.x;
    al[tid] = alpha[(size_t)tid * B_DIM + b];
    __syncthreads();
    int c8 = tid & 63, tq = tid >> 6;
    float acc[8] = {};
    for (int t = tq * 64; t < tq * 64 + 64; ++t) {
        const float* src = feats + ((size_t)(t * B_DIM + b)) * NIN + c8 * 8;
        float4 v0 = *reinterpret_cast<const float4*>(src);
        float4 v1 = *reinterpret_cast<const float4*>(src + 4);
        float a = al[t];
        acc[0] += a * v0.x; acc[1] += a * v0.y; acc[2] += a * v0.z; acc[3] += a * v0.w;
        acc[4] += a * v1.x; acc[5] += a * v1.y; acc[6] += a * v1.z; acc[7] += a * v1.w;
    }
#pragma unroll
    for (int j = 0; j < 8; ++j) red[tq][c8 * 8 + j] = acc[j];
    __syncthreads();
#pragma unroll
    for (int k = 0; k < 2; ++k) {
        int c = tid * 2 + k;
        float s = red[0][c] + red[1][c] + red[2][c] + red[3][c];
        x[(size_t)b * NX + c] = (bf16)s;
    }
    x[(size_t)b * NX + NIN + tid] = (bf16)emb[(size_t)b * NEMB + tid];
}

// ---------------- GRU gates ----------------
__global__ __launch_bounds__(256) void gru_kernel(
    const float* __restrict__ gi, const float* __restrict__ gh,
    const float* __restrict__ h, float* __restrict__ out) {
    int idx = blockIdx.x * 256 + threadIdx.x;
    int b = idx >> 9, j = idx & 511;
    const float* gib = gi + (size_t)b * NG;
    const float* ghb = gh + (size_t)b * NG;
    float r = fast_sigmoid(gib[j] + ghb[j]);
    float z = fast_sigmoid(gib[NH + j] + ghb[NH + j]);
    float n = fast_tanh(gib[2 * NH + j] + r * ghb[2 * NH + j]);
    out[idx] = (1.0f - z) * n + z * h[idx];
}

extern "C" void kernel_launch(void* const* d_in, const int* in_sizes, int n_in,
                              void* d_out, int out_size, void* d_ws, size_t ws_size,
                              hipStream_t stream) {
    const float* feats = (const float*)d_in[0];
    const float* h     = (const float*)d_in[1];
    const float* emb   = (const float*)d_in[2];
    const float* w_i2h = (const float*)d_in[3];
    const float* w_h2h = (const float*)d_in[4];
    const float* b_h2h = (const float*)d_in[5];
    const float* w_sc  = (const float*)d_in[6];
    const float* w_ih  = (const float*)d_in[7];
    const float* w_hh  = (const float*)d_in[8];
    const float* b_ih  = (const float*)d_in[9];
    const float* b_hh  = (const float*)d_in[10];
    float* out = (float*)d_out;

    char* ws = (char*)d_ws;
    bf16*  Wimg    = (bf16*)(ws);                 // 524288 (swizzled K-step image)
    bf16*  w_h2h_b = (bf16*)(ws + 524288);        // 524288
    bf16*  w_ih_b  = (bf16*)(ws + 1048576);       // 2359296
    bf16*  w_hh_b  = (bf16*)(ws + 3407872);       // 1572864
    bf16*  h_b     = (bf16*)(ws + 4980736);       // 262144
    bf16*  x_b     = (bf16*)(ws + 5242880);       // 393216
    float* hbuf    = (float*)(ws + 5636096);      // 524288
    float* emit    = (float*)(ws + 6160384);      // 262144
    float* alpha   = (float*)(ws + 6422528);      // 262144
    float* gi      = (float*)(ws + 6684672);      // 1572864
    float* gh      = (float*)(ws + 8257536);      // 1572864  -> total 9830400

    // 1) weight/h conversions (w_i2h -> swizzled Wimg)
    cvt_weights<<<1024, 256, 0, stream>>>(w_i2h, w_h2h, w_ih, w_hh, h,
                                          Wimg, w_h2h_b, w_ih_b, w_hh_b, h_b);

    // 2) h_ = h @ w_h2h^T + b_h2h ; gh = h @ w_hh^T + b_hh (independent of emit)
    gemm_bias<<<dim3(8, 4), 256, 0, stream>>>(h_b, w_h2h_b, b_h2h, hbuf, 256, NH, NH);
    gemm_bias<<<dim3(24, 4), 256, 0, stream>>>(h_b, w_hh_b, b_hh, gh, 256, NG, NH);

    // 3) fused emit (reads f32 feats directly)
    emit_kernel<<<1024, 512, 0, stream>>>(feats, Wimg, hbuf, w_sc, emit);

    // 4) alpha = softmax_T(emit); also output 1
    softmax_t<<<256, 256, 0, stream>>>(emit, alpha, out + 131072);

    // 5) context + x build (fused, f32 feats from L3)
    ctx_kernel<<<256, 256, 0, stream>>>(feats, alpha, emb, x_b);

    // 6) gi = x @ w_ih^T + b_ih
    gemm_bias<<<dim3(24, 4), 256, 0, stream>>>(x_b, w_ih_b, b_ih, gi, 256, NG, NX);

    // 7) GRU -> nh (output 0)
    gru_kernel<<<512, 256, 0, stream>>>(gi, gh, h, out);
}

// Round 8
// 127.459 us; speedup vs baseline: 1.1059x; 1.1059x over previous
//
#include <hip/hip_runtime.h>

typedef __bf16 bf16;
typedef __bf16 bf16x4 __attribute__((ext_vector_type(4)));
typedef __bf16 bf16x8 __attribute__((ext_vector_type(8)));
typedef float  f32x4  __attribute__((ext_vector_type(4)));

#define T_DIM 256
#define B_DIM 256
#define NIN   512
#define NH    512
#define NEMB  256
#define NX    768      // NIN + NEMB
#define NG    1536     // 3*NH
#define MTOT  65536    // T*B

__device__ __forceinline__ float fast_tanh(float x) {
    float e = __expf(2.0f * x);
    return 1.0f - 2.0f * __builtin_amdgcn_rcpf(e + 1.0f);
}
__device__ __forceinline__ float fast_sigmoid(float x) {
    return __builtin_amdgcn_rcpf(1.0f + __expf(-x));
}

__device__ __forceinline__ void gload_lds16(const bf16* g, bf16* l) {
    __builtin_amdgcn_global_load_lds(
        (const __attribute__((address_space(1))) void*)g,
        (__attribute__((address_space(3))) void*)l, 16, 0, 0);
}

// chunk swizzle: rows of 32 bf16 = 4 chunks of 8; slot = chunk ^ ((row>>1)&3)
// (this family measured SQ_LDS_BANK_CONFLICT == 0 in rounds 3/4/6)
__device__ __forceinline__ int csw(int row) { return (row >> 1) & 3; }

// ---------------- weight/h conversion (all linear bf16) ----------------
__global__ __launch_bounds__(256) void cvt_weights(
    const float* __restrict__ a0, const float* __restrict__ a1,
    const float* __restrict__ a2, const float* __restrict__ a3,
    const float* __restrict__ a4,
    bf16* __restrict__ b0, bf16* __restrict__ b1, bf16* __restrict__ b2,
    bf16* __restrict__ b3, bf16* __restrict__ b4) {
    const int N0 = 65536, N1 = 131072, N2 = 425984, N3 = 622592, N4 = 655360;
    for (int i = blockIdx.x * 256 + threadIdx.x; i < N4; i += gridDim.x * 256) {
        const float* s; bf16* d; int j;
        if (i < N0)      { s = a0; d = b0; j = i; }
        else if (i < N1) { s = a1; d = b1; j = i - N0; }
        else if (i < N2) { s = a2; d = b2; j = i - N1; }
        else if (i < N3) { s = a3; d = b3; j = i - N2; }
        else             { s = a4; d = b4; j = i - N3; }
        float4 v = reinterpret_cast<const float4*>(s)[j];
        bf16x4 o = { (bf16)v.x, (bf16)v.y, (bf16)v.z, (bf16)v.w };
        reinterpret_cast<bf16x4*>(d)[j] = o;
    }
}

// ---------------- generic GEMM: C[M,N] = A[M,K] * B[N,K]^T + bias[N] ----------------
__global__ __launch_bounds__(256) void gemm_bias(
    const bf16* __restrict__ A, const bf16* __restrict__ B,
    const float* __restrict__ bias, float* __restrict__ C,
    int M, int N, int K) {
    __shared__ bf16 At[64][40];
    __shared__ bf16 Bt[64][40];
    const int tid = threadIdx.x;
    const int m0 = blockIdx.y * 64, n0 = blockIdx.x * 64;
    const int wid = tid >> 6, lane = tid & 63, hi = lane >> 4, lo = lane & 15;
    const int srow = tid >> 2, sseg = tid & 3;
    f32x4 acc[4] = {};

    for (int kk = 0; kk < K; kk += 32) {
        bf16x8 av = *reinterpret_cast<const bf16x8*>(A + (size_t)(m0 + srow) * K + kk + sseg * 8);
        bf16x8 bv = *reinterpret_cast<const bf16x8*>(B + (size_t)(n0 + srow) * K + kk + sseg * 8);
        __syncthreads();
        *reinterpret_cast<bf16x8*>(&At[srow][sseg * 8]) = av;
        *reinterpret_cast<bf16x8*>(&Bt[srow][sseg * 8]) = bv;
        __syncthreads();
        bf16x8 a = *reinterpret_cast<const bf16x8*>(&At[wid * 16 + lo][hi * 8]);
#pragma unroll
        for (int nt = 0; nt < 4; ++nt) {
            bf16x8 b = *reinterpret_cast<const bf16x8*>(&Bt[nt * 16 + lo][hi * 8]);
            acc[nt] = __builtin_amdgcn_mfma_f32_16x16x32_bf16(a, b, acc[nt], 0, 0, 0);
        }
    }
#pragma unroll
    for (int nt = 0; nt < 4; ++nt) {
        int n = n0 + nt * 16 + lo;
        float bv = bias[n];
#pragma unroll
        for (int r = 0; r < 4; ++r) {
            int m = m0 + wid * 16 + hi * 4 + r;
            C[(size_t)m * N + n] = acc[nt][r] + bv;
        }
    }
}

// ---------------- fused emit kernel (v7: m97-clone, 4-wave blocks, ~4 blocks/CU) --------
// Tile 128m x 128n, BK=32, 16 K-steps, single-buffered LDS, 2 barriers/step.
// A: reg-staged f32->bf16 (feats read once). B: global_load_lds from linear bf16 W,
// per-lane pre-swizzled source. Writes emit_part[nb][m] (4 n-partials).
__global__ __launch_bounds__(256, 3) void emit_kernel(
    const float* __restrict__ feats, const bf16* __restrict__ Wb,
    const float* __restrict__ hbuf, const float* __restrict__ wscore,
    float* __restrict__ emit_part) {
    __shared__ bf16 At[128 * 32];   // 8 KB
    __shared__ bf16 Bt[128 * 32];   // 8 KB
    __shared__ float ew[4][64];     // 1 KB
    const int tid = threadIdx.x;
    // XCD-chunked tile map: 4 n-blocks of the same m-strip land on one XCD's L2
    const int tile = (blockIdx.x & 7) * 256 + (blockIdx.x >> 3);
    const int nb = tile & 3, mb = tile >> 2;
    const int m0 = mb * 128, n0g = nb * 128;
    const int wid = tid >> 6, lane = tid & 63, hi = lane >> 4, lo = lane & 15;
    const int wr = wid >> 1, wc = wid & 1;

    // staging map: chunkid = j*256 + tid (j=0,1); row = chunkid>>2, c = chunkid&3
    const int ar0 = tid >> 2, ac0 = tid & 3;          // j=0: rows 0..63
    const int ar1 = 64 + ar0, ac1 = ac0;              // j=1: rows 64..127
    // A: linear global chunk -> swizzled LDS slot (ds_write addr carries the XOR)
    const float* as0 = feats + (size_t)(m0 + ar0) * NIN + ac0 * 8;
    const float* as1 = feats + (size_t)(m0 + ar1) * NIN + ac1 * 8;
    bf16* aw0 = At + ar0 * 32 + ((ac0 ^ csw(ar0)) * 8);
    bf16* aw1 = At + ar1 * 32 + ((ac1 ^ csw(ar1)) * 8);
    // B: swizzled global source chunk -> linear LDS dest (gload_lds: base + lane*16)
    const bf16* bs0 = Wb + (size_t)(n0g + ar0) * NIN + ((ac0 ^ csw(ar0)) * 8);
    const bf16* bs1 = Wb + (size_t)(n0g + ar1) * NIN + ((ac1 ^ csw(ar1)) * 8);
    bf16* bd0 = Bt + wid * 512;           // + lane*8 elems by HW
    bf16* bd1 = Bt + 2048 + wid * 512;

    // prologue: A(0) f32 in regs
    float4 f00 = *reinterpret_cast<const float4*>(as0);
    float4 f01 = *reinterpret_cast<const float4*>(as0 + 4);
    float4 f10 = *reinterpret_cast<const float4*>(as1);
    float4 f11 = *reinterpret_cast<const float4*>(as1 + 4);

    f32x4 acc[4][4] = {};   // [nt][st]
#pragma unroll
    for (int kk = 0; kk < 16; ++kk) {
        if (kk > 0) __syncthreads();     // previous step's LDS readers done
        // stage A(kk): cvt f32 regs -> bf16 LDS (swizzled slots)
        bf16x8 o0 = { (bf16)f00.x, (bf16)f00.y, (bf16)f00.z, (bf16)f00.w,
                      (bf16)f01.x, (bf16)f01.y, (bf16)f01.z, (bf16)f01.w };
        bf16x8 o1 = { (bf16)f10.x, (bf16)f10.y, (bf16)f10.z, (bf16)f10.w,
                      (bf16)f11.x, (bf16)f11.y, (bf16)f11.z, (bf16)f11.w };
        *reinterpret_cast<bf16x8*>(aw0) = o0;
        *reinterpret_cast<bf16x8*>(aw1) = o1;
        // stage B(kk): DMA
        gload_lds16(bs0 + kk * 32, bd0);
        gload_lds16(bs1 + kk * 32, bd1);
        __syncthreads();                 // drains: B(kk) landed, A writes visible
        // issue A(kk+1) f32 loads now; MFMA below covers part of their latency
        if (kk < 15) {
            f00 = *reinterpret_cast<const float4*>(as0 + (kk + 1) * 32);
            f01 = *reinterpret_cast<const float4*>(as0 + (kk + 1) * 32 + 4);
            f10 = *reinterpret_cast<const float4*>(as1 + (kk + 1) * 32);
            f11 = *reinterpret_cast<const float4*>(as1 + (kk + 1) * 32 + 4);
        }
        // fragments + MFMA
        bf16x8 a[4], b[4];
#pragma unroll
        for (int st = 0; st < 4; ++st) {
            int row = wr * 64 + st * 16 + lo;
            a[st] = *reinterpret_cast<const bf16x8*>(
                At + row * 32 + ((hi ^ csw(row)) * 8));
        }
#pragma unroll
        for (int nt = 0; nt < 4; ++nt) {
            int col = wc * 64 + nt * 16 + lo;
            b[nt] = *reinterpret_cast<const bf16x8*>(
                Bt + col * 32 + ((hi ^ csw(col)) * 8));
        }
#pragma unroll
        for (int nt = 0; nt < 4; ++nt)
#pragma unroll
            for (int st = 0; st < 4; ++st)
                acc[nt][st] = __builtin_amdgcn_mfma_f32_16x16x32_bf16(
                    a[st], b[nt], acc[nt][st], 0, 0, 0);
    }

    // epilogue: add h_, tanh, dot with w_score -> per-block n-partials
    float ep[4][4] = {};                 // [st][r]
    const int bbase = m0 & (B_DIM - 1);  // 0 or 128
#pragma unroll
    for (int nt = 0; nt < 4; ++nt) {
        int n = n0g + wc * 64 + nt * 16 + lo;
        float wsn = wscore[n];
#pragma unroll
        for (int st = 0; st < 4; ++st) {
#pragma unroll
            for (int r = 0; r < 4; ++r) {
                int b = bbase + wr * 64 + st * 16 + hi * 4 + r;
                float x = acc[nt][st][r] + hbuf[(size_t)b * NH + n];
                ep[st][r] += fast_tanh(x) * wsn;
            }
        }
    }
#pragma unroll
    for (int st = 0; st < 4; ++st)
#pragma unroll
        for (int r = 0; r < 4; ++r)
#pragma unroll
            for (int off = 1; off < 16; off <<= 1)
                ep[st][r] += __shfl_xor(ep[st][r], off, 64);

    if (lo == 0) {
#pragma unroll
        for (int st = 0; st < 4; ++st)
#pragma unroll
            for (int r = 0; r < 4; ++r)
                ew[wid][st * 16 + hi * 4 + r] = ep[st][r];
    }
    __syncthreads();
    if (tid < 128) {
        float s = ew[(tid >> 6) * 2][tid & 63] + ew[(tid >> 6) * 2 + 1][tid & 63];
        emit_part[(size_t)nb * MTOT + m0 + tid] = s;
    }
}

// ---------------- softmax over T (per column b), summing 4 n-partials ----------------
__global__ __launch_bounds__(256) void softmax_t(
    const float* __restrict__ emit_part, float* __restrict__ alpha,
    float* __restrict__ out_alpha) {
    int b = blockIdx.x, t = threadIdx.x;
    int wv = t >> 6, ln = t & 63;
    size_t m = (size_t)t * B_DIM + b;
    float e = emit_part[m] + emit_part[MTOT + m] +
              emit_part[2 * MTOT + m] + emit_part[3 * MTOT + m];
    float mx = e;
#pragma unroll
    for (int off = 32; off; off >>= 1) mx = fmaxf(mx, __shfl_xor(mx, off, 64));
    __shared__ float red[4], red2[4];
    if (ln == 0) red[wv] = mx;
    __syncthreads();
    mx = fmaxf(fmaxf(red[0], red[1]), fmaxf(red[2], red[3]));
    float p = __expf(e - mx);
    float s = p;
#pragma unroll
    for (int off = 32; off; off >>= 1) s += __shfl_xor(s, off, 64);
    if (ln == 0) red2[wv] = s;
    __syncthreads();
    float inv = __builtin_amdgcn_rcpf(red2[0] + red2[1] + red2[2] + red2[3]);
    float a = p * inv;
    alpha[m] = a;
    out_alpha[m] = a;
}

// ---------------- context + build_x fused (reads f32 feats, L3-resident) ----------------
__global__ __launch_bounds__(256) void ctx_kernel(
    const float* __restrict__ feats, const float* __restrict__ alpha,
    const float* __restrict__ emb, bf16* __restrict__ x) {
    int b = blockIdx.x;
    __shared__ float al[T_DIM];
    __shared__ float red[4][512];
    int tid = threadIdx.x;
    al[tid] = alpha[(size_t)tid * B_DIM + b];
    __syncthreads();
    int c8 = tid & 63, tq = tid >> 6;
    float acc[8] = {};
#pragma unroll 4
    for (int t = tq * 64; t < tq * 64 + 64; ++t) {
        const float* src = feats + ((size_t)(t * B_DIM + b)) * NIN + c8 * 8;
        float4 v0 = *reinterpret_cast<const float4*>(src);
        float4 v1 = *reinterpret_cast<const float4*>(src + 4);
        float a = al[t];
        acc[0] += a * v0.x; acc[1] += a * v0.y; acc[2] += a * v0.z; acc[3] += a * v0.w;
        acc[4] += a * v1.x; acc[5] += a * v1.y; acc[6] += a * v1.z; acc[7] += a * v1.w;
    }
#pragma unroll
    for (int j = 0; j < 8; ++j) red[tq][c8 * 8 + j] = acc[j];
    __syncthreads();
#pragma unroll
    for (int k = 0; k < 2; ++k) {
        int c = tid * 2 + k;
        float s = red[0][c] + red[1][c] + red[2][c] + red[3][c];
        x[(size_t)b * NX + c] = (bf16)s;
    }
    x[(size_t)b * NX + NIN + tid] = (bf16)emb[(size_t)b * NEMB + tid];
}

// ---------------- GRU gates ----------------
__global__ __launch_bounds__(256) void gru_kernel(
    const float* __restrict__ gi, const float* __restrict__ gh,
    const float* __restrict__ h, float* __restrict__ out) {
    int idx = blockIdx.x * 256 + threadIdx.x;
    int b = idx >> 9, j = idx & 511;
    const float* gib = gi + (size_t)b * NG;
    const float* ghb = gh + (size_t)b * NG;
    float r = fast_sigmoid(gib[j] + ghb[j]);
    float z = fast_sigmoid(gib[NH + j] + ghb[NH + j]);
    float n = fast_tanh(gib[2 * NH + j] + r * ghb[2 * NH + j]);
    out[idx] = (1.0f - z) * n + z * h[idx];
}

extern "C" void kernel_launch(void* const* d_in, const int* in_sizes, int n_in,
                              void* d_out, int out_size, void* d_ws, size_t ws_size,
                              hipStream_t stream) {
    const float* feats = (const float*)d_in[0];
    const float* h     = (const float*)d_in[1];
    const float* emb   = (const float*)d_in[2];
    const float* w_i2h = (const float*)d_in[3];
    const float* w_h2h = (const float*)d_in[4];
    const float* b_h2h = (const float*)d_in[5];
    const float* w_sc  = (const float*)d_in[6];
    const float* w_ih  = (const float*)d_in[7];
    const float* w_hh  = (const float*)d_in[8];
    const float* b_ih  = (const float*)d_in[9];
    const float* b_hh  = (const float*)d_in[10];
    float* out = (float*)d_out;

    char* ws = (char*)d_ws;
    bf16*  w_i2h_b = (bf16*)(ws);                 // 524288
    bf16*  w_h2h_b = (bf16*)(ws + 524288);        // 524288
    bf16*  w_ih_b  = (bf16*)(ws + 1048576);       // 2359296
    bf16*  w_hh_b  = (bf16*)(ws + 3407872);       // 1572864
    bf16*  h_b     = (bf16*)(ws + 4980736);       // 262144
    bf16*  x_b     = (bf16*)(ws + 5242880);       // 393216
    float* hbuf    = (float*)(ws + 5636096);      // 524288
    float* emit_p  = (float*)(ws + 6160384);      // 1048576 (4 partials)
    float* alpha   = (float*)(ws + 7208960);      // 262144
    float* gi      = (float*)(ws + 7471104);      // 1572864
    float* gh      = (float*)(ws + 9043968);      // 1572864  -> total 10616832

    // 1) weight/h conversions (all linear bf16)
    cvt_weights<<<1024, 256, 0, stream>>>(w_i2h, w_h2h, w_ih, w_hh, h,
                                          w_i2h_b, w_h2h_b, w_ih_b, w_hh_b, h_b);

    // 2) h_ = h @ w_h2h^T + b_h2h ; gh = h @ w_hh^T + b_hh
    gemm_bias<<<dim3(8, 4), 256, 0, stream>>>(h_b, w_h2h_b, b_h2h, hbuf, 256, NH, NH);
    gemm_bias<<<dim3(24, 4), 256, 0, stream>>>(h_b, w_hh_b, b_hh, gh, 256, NG, NH);

    // 3) fused emit (m97-structure; reads f32 feats directly)
    emit_kernel<<<2048, 256, 0, stream>>>(feats, w_i2h_b, hbuf, w_sc, emit_p);

    // 4) alpha = softmax_T(sum of partials); also output 1
    softmax_t<<<256, 256, 0, stream>>>(emit_p, alpha, out + 131072);

    // 5) context + x build (fused, f32 feats from L3)
    ctx_kernel<<<256, 256, 0, stream>>>(feats, alpha, emb, x_b);

    // 6) gi = x @ w_ih^T + b_ih
    gemm_bias<<<dim3(24, 4), 256, 0, stream>>>(x_b, w_ih_b, b_ih, gi, 256, NG, NX);

    // 7) GRU -> nh (output 0)
    gru_kernel<<<512, 256, 0, stream>>>(gi, gh, h, out);
}

// Round 9
// 123.149 us; speedup vs baseline: 1.1446x; 1.0350x over previous
//
#include <hip/hip_runtime.h>

typedef __bf16 bf16;
typedef __bf16 bf16x4 __attribute__((ext_vector_type(4)));
typedef __bf16 bf16x8 __attribute__((ext_vector_type(8)));
typedef float  f32x4  __attribute__((ext_vector_type(4)));

#define T_DIM 256
#define B_DIM 256
#define NIN   512
#define NH    512
#define NEMB  256
#define NX    768      // NIN + NEMB
#define NG    1536     // 3*NH
#define MTOT  65536    // T*B

__device__ __forceinline__ float fast_tanh(float x) {
    float e = __expf(2.0f * x);
    return 1.0f - 2.0f * __builtin_amdgcn_rcpf(e + 1.0f);
}
__device__ __forceinline__ float fast_sigmoid(float x) {
    return __builtin_amdgcn_rcpf(1.0f + __expf(-x));
}

__device__ __forceinline__ void gload_lds16(const bf16* g, bf16* l) {
    __builtin_amdgcn_global_load_lds(
        (const __attribute__((address_space(1))) void*)g,
        (__attribute__((address_space(3))) void*)l, 16, 0, 0);
}

// ---------------- weight/h conversion; w_i2h -> step-major swizzled image --------
// rows of 64 bf16 = 8 chunks of 8; slot = chunk ^ (row&7)  (0-conflict family)
// Wimg[s][col][slot*8+within] = w_i2h[col][s*64 + k],  s<8, col<512, k<64
__global__ __launch_bounds__(256) void cvt_weights(
    const float* __restrict__ a0, const float* __restrict__ a1,
    const float* __restrict__ a2, const float* __restrict__ a3,
    const float* __restrict__ a4,
    bf16* __restrict__ b0, bf16* __restrict__ b1, bf16* __restrict__ b2,
    bf16* __restrict__ b3, bf16* __restrict__ b4) {
    const int N0 = 65536, N1 = 131072, N2 = 425984, N3 = 622592, N4 = 655360;
    for (int i = blockIdx.x * 256 + threadIdx.x; i < N4; i += gridDim.x * 256) {
        const float* s; bf16* d; int j; bool img = false;
        if (i < N0)      { s = a0; d = b0; j = i; img = true; }
        else if (i < N1) { s = a1; d = b1; j = i - N0; }
        else if (i < N2) { s = a2; d = b2; j = i - N1; }
        else if (i < N3) { s = a3; d = b3; j = i - N2; }
        else             { s = a4; d = b4; j = i - N3; }
        float4 v = reinterpret_cast<const float4*>(s)[j];
        bf16x4 o = { (bf16)v.x, (bf16)v.y, (bf16)v.z, (bf16)v.w };
        if (img) {
            int e = j * 4, col = e >> 9, K = e & 511;
            int st = K >> 6, k = K & 63, chunk = k >> 3, within = k & 7;
            int slot = chunk ^ (col & 7);
            *reinterpret_cast<bf16x4*>(d + st * 32768 + col * 64 + slot * 8 + within) = o;
        } else {
            reinterpret_cast<bf16x4*>(d)[j] = o;
        }
    }
}

// ---------------- generic GEMM: C[M,N] = A[M,K] * B[N,K]^T + bias[N] ----------------
__global__ __launch_bounds__(256) void gemm_bias(
    const bf16* __restrict__ A, const bf16* __restrict__ B,
    const float* __restrict__ bias, float* __restrict__ C,
    int M, int N, int K) {
    __shared__ bf16 At[64][40];
    __shared__ bf16 Bt[64][40];
    const int tid = threadIdx.x;
    const int m0 = blockIdx.y * 64, n0 = blockIdx.x * 64;
    const int wid = tid >> 6, lane = tid & 63, hi = lane >> 4, lo = lane & 15;
    const int srow = tid >> 2, sseg = tid & 3;
    f32x4 acc[4] = {};

    for (int kk = 0; kk < K; kk += 32) {
        bf16x8 av = *reinterpret_cast<const bf16x8*>(A + (size_t)(m0 + srow) * K + kk + sseg * 8);
        bf16x8 bv = *reinterpret_cast<const bf16x8*>(B + (size_t)(n0 + srow) * K + kk + sseg * 8);
        __syncthreads();
        *reinterpret_cast<bf16x8*>(&At[srow][sseg * 8]) = av;
        *reinterpret_cast<bf16x8*>(&Bt[srow][sseg * 8]) = bv;
        __syncthreads();
        bf16x8 a = *reinterpret_cast<const bf16x8*>(&At[wid * 16 + lo][hi * 8]);
#pragma unroll
        for (int nt = 0; nt < 4; ++nt) {
            bf16x8 b = *reinterpret_cast<const bf16x8*>(&Bt[nt * 16 + lo][hi * 8]);
            acc[nt] = __builtin_amdgcn_mfma_f32_16x16x32_bf16(a, b, acc[nt], 0, 0, 0);
        }
    }
#pragma unroll
    for (int nt = 0; nt < 4; ++nt) {
        int n = n0 + nt * 16 + lo;
        float bv = bias[n];
#pragma unroll
        for (int r = 0; r < 4; ++r) {
            int m = m0 + wid * 16 + hi * 4 + r;
            C[(size_t)m * N + n] = acc[nt][r] + bv;
        }
    }
}

// ---------------- fused emit kernel (v8: fat windows — 128m x 512n, BK=64, 8 steps) ----
// emit[m] = sum_n tanh((feats W^T)[m,n] + h_[b(m),n]) * w_score[n]
// Block: 512 thr (8 waves); wave w owns cols w*64..w*64+63 and ALL 128 rows.
// Per step per wave: 64 MFMA vs 24 ds_read_b128 — compute dominates the sync window.
__global__ __launch_bounds__(512, 2) void emit_kernel(
    const float* __restrict__ feats, const bf16* __restrict__ Wimg,
    const float* __restrict__ hbuf, const float* __restrict__ wscore,
    float* __restrict__ emit_out) {
    __shared__ bf16 Bt[512 * 64];   // 64 KB  [col][slot8 ^ (col&7)]
    __shared__ bf16 At[128 * 64];   // 16 KB  [row][slot8 ^ (row&7)]
    __shared__ float ew[8][128];    // 4 KB
    const int tid = threadIdx.x;
    const int m0 = blockIdx.x * 128;
    const int wid = tid >> 6, lane = tid & 63, hi = lane >> 4, lo = lane & 15;

    // A staging coords: thread -> (row, 16-float k-segment)
    const int arow = tid >> 2, ac = tid & 3;              // row 0..127, c 0..3
    const float* asrc = feats + (size_t)(m0 + arow) * NIN + ac * 16;
    bf16* aw0 = At + arow * 64 + (((2 * ac) ^ (arow & 7)) * 8);
    bf16* aw1 = At + arow * 64 + (((2 * ac + 1) ^ (arow & 7)) * 8);

    float4 va0, va1, va2, va3;
    // ---- prologue: A(0) loads, B(0) DMA, stage, one drain ----
    va0 = *reinterpret_cast<const float4*>(asrc);
    va1 = *reinterpret_cast<const float4*>(asrc + 4);
    va2 = *reinterpret_cast<const float4*>(asrc + 8);
    va3 = *reinterpret_cast<const float4*>(asrc + 12);
#pragma unroll
    for (int r = 0; r < 8; ++r)
        gload_lds16(Wimg + r * 4096 + wid * 512 + lane * 8,
                    Bt + r * 4096 + wid * 512);
    {
        bf16x8 o0 = { (bf16)va0.x, (bf16)va0.y, (bf16)va0.z, (bf16)va0.w,
                      (bf16)va1.x, (bf16)va1.y, (bf16)va1.z, (bf16)va1.w };
        bf16x8 o1 = { (bf16)va2.x, (bf16)va2.y, (bf16)va2.z, (bf16)va2.w,
                      (bf16)va3.x, (bf16)va3.y, (bf16)va3.z, (bf16)va3.w };
        *reinterpret_cast<bf16x8*>(aw0) = o0;
        *reinterpret_cast<bf16x8*>(aw1) = o1;
    }
    __syncthreads();

    f32x4 acc[8][4] = {};   // [st][nt] -> AGPRs
    for (int s = 0; s < 8; ++s) {
        // issue A(s+1) loads; covered by this step's 64-MFMA window
        if (s < 7) {
            const float* an = asrc + (s + 1) * 64;
            va0 = *reinterpret_cast<const float4*>(an);
            va1 = *reinterpret_cast<const float4*>(an + 4);
            va2 = *reinterpret_cast<const float4*>(an + 8);
            va3 = *reinterpret_cast<const float4*>(an + 12);
        }
        // b-frags for this wave's 64 cols (8 reads)
        bf16x8 b[4][2];
#pragma unroll
        for (int nt = 0; nt < 4; ++nt) {
            int col = wid * 64 + nt * 16 + lo;
#pragma unroll
            for (int k2 = 0; k2 < 2; ++k2)
                b[nt][k2] = *reinterpret_cast<const bf16x8*>(
                    Bt + col * 64 + (((k2 * 4 + hi) ^ (col & 7)) * 8));
        }
        // 8 row-tiles x 4 col-tiles x 2 k-sub = 64 MFMA
#pragma unroll
        for (int st = 0; st < 8; ++st) {
            int row = st * 16 + lo;
            bf16x8 a0 = *reinterpret_cast<const bf16x8*>(
                At + row * 64 + ((hi ^ (row & 7)) * 8));
            bf16x8 a1 = *reinterpret_cast<const bf16x8*>(
                At + row * 64 + (((4 + hi) ^ (row & 7)) * 8));
#pragma unroll
            for (int nt = 0; nt < 4; ++nt) {
                acc[st][nt] = __builtin_amdgcn_mfma_f32_16x16x32_bf16(a0, b[nt][0], acc[st][nt], 0, 0, 0);
                acc[st][nt] = __builtin_amdgcn_mfma_f32_16x16x32_bf16(a1, b[nt][1], acc[st][nt], 0, 0, 0);
            }
        }
        __syncthreads();                 // readers of step s done
        if (s < 7) {
            bf16x8 o0 = { (bf16)va0.x, (bf16)va0.y, (bf16)va0.z, (bf16)va0.w,
                          (bf16)va1.x, (bf16)va1.y, (bf16)va1.z, (bf16)va1.w };
            bf16x8 o1 = { (bf16)va2.x, (bf16)va2.y, (bf16)va2.z, (bf16)va2.w,
                          (bf16)va3.x, (bf16)va3.y, (bf16)va3.z, (bf16)va3.w };
            *reinterpret_cast<bf16x8*>(aw0) = o0;
            *reinterpret_cast<bf16x8*>(aw1) = o1;
#pragma unroll
            for (int r = 0; r < 8; ++r)
                gload_lds16(Wimg + (s + 1) * 32768 + r * 4096 + wid * 512 + lane * 8,
                            Bt + r * 4096 + wid * 512);
            __syncthreads();             // staging visible (DMA drained here)
        }
    }

    // ---- epilogue: add h_, tanh, dot w_score; reduce 16 lanes then 8 waves ----
    const int bbase = m0 & (B_DIM - 1);
    float ws4[4];
#pragma unroll
    for (int nt = 0; nt < 4; ++nt) ws4[nt] = wscore[wid * 64 + nt * 16 + lo];
    float ep[8][4];
#pragma unroll
    for (int st = 0; st < 8; ++st) {
#pragma unroll
        for (int r = 0; r < 4; ++r) {
            int brow = bbase + st * 16 + hi * 4 + r;
            const float* hp = hbuf + (size_t)brow * NH + wid * 64 + lo;
            float e = 0.0f;
#pragma unroll
            for (int nt = 0; nt < 4; ++nt)
                e += fast_tanh(acc[st][nt][r] + hp[nt * 16]) * ws4[nt];
            ep[st][r] = e;
        }
    }
#pragma unroll
    for (int st = 0; st < 8; ++st)
#pragma unroll
        for (int r = 0; r < 4; ++r)
#pragma unroll
            for (int off = 1; off < 16; off <<= 1)
                ep[st][r] += __shfl_xor(ep[st][r], off, 64);

    if (lo == 0) {
#pragma unroll
        for (int st = 0; st < 8; ++st)
#pragma unroll
            for (int r = 0; r < 4; ++r)
                ew[wid][st * 16 + hi * 4 + r] = ep[st][r];
    }
    __syncthreads();
    if (tid < 128) {
        float sacc = 0.0f;
#pragma unroll
        for (int ww = 0; ww < 8; ++ww) sacc += ew[ww][tid];
        emit_out[m0 + tid] = sacc;
    }
}

// ---------------- softmax over T (per column b) ----------------
__global__ __launch_bounds__(256) void softmax_t(
    const float* __restrict__ emit, float* __restrict__ alpha,
    float* __restrict__ out_alpha) {
    int b = blockIdx.x, t = threadIdx.x;
    int wv = t >> 6, ln = t & 63;
    size_t m = (size_t)t * B_DIM + b;
    float e = emit[m];
    float mx = e;
#pragma unroll
    for (int off = 32; off; off >>= 1) mx = fmaxf(mx, __shfl_xor(mx, off, 64));
    __shared__ float red[4], red2[4];
    if (ln == 0) red[wv] = mx;
    __syncthreads();
    mx = fmaxf(fmaxf(red[0], red[1]), fmaxf(red[2], red[3]));
    float p = __expf(e - mx);
    float s = p;
#pragma unroll
    for (int off = 32; off; off >>= 1) s += __shfl_xor(s, off, 64);
    if (ln == 0) red2[wv] = s;
    __syncthreads();
    float inv = __builtin_amdgcn_rcpf(red2[0] + red2[1] + red2[2] + red2[3]);
    float a = p * inv;
    alpha[m] = a;
    out_alpha[m] = a;
}

// ---------------- context + build_x fused (reads f32 feats, L3-resident) ----------------
__global__ __launch_bounds__(256) void ctx_kernel(
    const float* __restrict__ feats, const float* __restrict__ alpha,
    const float* __restrict__ emb, bf16* __restrict__ x) {
    int b = blockIdx.x;
    __shared__ float al[T_DIM];
    __shared__ float red[4][512];
    int tid = threadIdx.x;
    al[tid] = alpha[(size_t)tid * B_DIM + b];
    __syncthreads();
    int c8 = tid & 63, tq = tid >> 6;
    float acc[8] = {};
#pragma unroll 4
    for (int t = tq * 64; t < tq * 64 + 64; ++t) {
        const float* src = feats + ((size_t)(t * B_DIM + b)) * NIN + c8 * 8;
        float4 v0 = *reinterpret_cast<const float4*>(src);
        float4 v1 = *reinterpret_cast<const float4*>(src + 4);
        float a = al[t];
        acc[0] += a * v0.x; acc[1] += a * v0.y; acc[2] += a * v0.z; acc[3] += a * v0.w;
        acc[4] += a * v1.x; acc[5] += a * v1.y; acc[6] += a * v1.z; acc[7] += a * v1.w;
    }
#pragma unroll
    for (int j = 0; j < 8; ++j) red[tq][c8 * 8 + j] = acc[j];
    __syncthreads();
#pragma unroll
    for (int k = 0; k < 2; ++k) {
        int c = tid * 2 + k;
        float s = red[0][c] + red[1][c] + red[2][c] + red[3][c];
        x[(size_t)b * NX + c] = (bf16)s;
    }
    x[(size_t)b * NX + NIN + tid] = (bf16)emb[(size_t)b * NEMB + tid];
}

// ---------------- GRU gates ----------------
__global__ __launch_bounds__(256) void gru_kernel(
    const float* __restrict__ gi, const float* __restrict__ gh,
    const float* __restrict__ h, float* __restrict__ out) {
    int idx = blockIdx.x * 256 + threadIdx.x;
    int b = idx >> 9, j = idx & 511;
    const float* gib = gi + (size_t)b * NG;
    const float* ghb = gh + (size_t)b * NG;
    float r = fast_sigmoid(gib[j] + ghb[j]);
    float z = fast_sigmoid(gib[NH + j] + ghb[NH + j]);
    float n = fast_tanh(gib[2 * NH + j] + r * ghb[2 * NH + j]);
    out[idx] = (1.0f - z) * n + z * h[idx];
}

extern "C" void kernel_launch(void* const* d_in, const int* in_sizes, int n_in,
                              void* d_out, int out_size, void* d_ws, size_t ws_size,
                              hipStream_t stream) {
    const float* feats = (const float*)d_in[0];
    const float* h     = (const float*)d_in[1];
    const float* emb   = (const float*)d_in[2];
    const float* w_i2h = (const float*)d_in[3];
    const float* w_h2h = (const float*)d_in[4];
    const float* b_h2h = (const float*)d_in[5];
    const float* w_sc  = (const float*)d_in[6];
    const float* w_ih  = (const float*)d_in[7];
    const float* w_hh  = (const float*)d_in[8];
    const float* b_ih  = (const float*)d_in[9];
    const float* b_hh  = (const float*)d_in[10];
    float* out = (float*)d_out;

    char* ws = (char*)d_ws;
    bf16*  Wimg    = (bf16*)(ws);                 // 524288 (step-major swizzled)
    bf16*  w_h2h_b = (bf16*)(ws + 524288);        // 524288
    bf16*  w_ih_b  = (bf16*)(ws + 1048576);       // 2359296
    bf16*  w_hh_b  = (bf16*)(ws + 3407872);       // 1572864
    bf16*  h_b     = (bf16*)(ws + 4980736);       // 262144
    bf16*  x_b     = (bf16*)(ws + 5242880);       // 393216
    float* hbuf    = (float*)(ws + 5636096);      // 524288
    float* emit    = (float*)(ws + 6160384);      // 262144
    float* alpha   = (float*)(ws + 6422528);      // 262144
    float* gi      = (float*)(ws + 6684672);      // 1572864
    float* gh      = (float*)(ws + 8257536);      // 1572864  -> total 9830400

    // 1) weight/h conversions (w_i2h -> step-major swizzled Wimg)
    cvt_weights<<<1024, 256, 0, stream>>>(w_i2h, w_h2h, w_ih, w_hh, h,
                                          Wimg, w_h2h_b, w_ih_b, w_hh_b, h_b);

    // 2) h_ = h @ w_h2h^T + b_h2h ; gh = h @ w_hh^T + b_hh
    gemm_bias<<<dim3(8, 4), 256, 0, stream>>>(h_b, w_h2h_b, b_h2h, hbuf, 256, NH, NH);
    gemm_bias<<<dim3(24, 4), 256, 0, stream>>>(h_b, w_hh_b, b_hh, gh, 256, NG, NH);

    // 3) fused emit (fat-window structure)
    emit_kernel<<<512, 512, 0, stream>>>(feats, Wimg, hbuf, w_sc, emit);

    // 4) alpha = softmax_T(emit); also output 1
    softmax_t<<<256, 256, 0, stream>>>(emit, alpha, out + 131072);

    // 5) context + x build (fused, f32 feats from L3)
    ctx_kernel<<<256, 256, 0, stream>>>(feats, alpha, emb, x_b);

    // 6) gi = x @ w_ih^T + b_ih
    gemm_bias<<<dim3(24, 4), 256, 0, stream>>>(x_b, w_ih_b, b_ih, gi, 256, NG, NX);

    // 7) GRU -> nh (output 0)
    gru_kernel<<<512, 256, 0, stream>>>(gi, gh, h, out);
}